// Round 17
// baseline (1683.944 us; speedup 1.0000x reference)
//
#include <hip/hip_runtime.h>
#include <math.h>

// Problem constants
#define BB 64      // batch
#define SS 512     // seq
#define EE 256     // embed
#define HH 512     // hidden

// Round-17: r16 batch-phase pipeline + LDS-ONLY phase barriers.
// r16 post-mortem: __syncthreads drains vmcnt(0) (gfx9 stores count in
// vmcnt), so finalize's LL-packet store had to ACK AT THE IC before the
// next phase barrier -- the store-ack the LL protocol was built to avoid,
// re-inserted 2x/step by barrier semantics. Fix: raw s_barrier preceded by
// s_waitcnt lgkmcnt(0) only (part[] is LDS; that's all the barrier must
// order), sched_barrier(0) fences both sides (rule #18). Packet stores and
// poll/xp loads stay in flight across the barrier; waves 0-3's store-ack
// folds into their next poll's own vmcnt(0) (max, not sum).
#define NGROUPS 16
#define GSLICES 8          // slices per layer per group
#define LBLK 16            // blocks per group (2 layers x 8 slices)
#define BPG 4              // batches per group
#define BPP 2              // batches per phase
#define RECT 512           // threads per rec block
#define RING 64            // ring slots per (layer,phase) chain
#define BARK 32            // full barrier every BARK steps

#define SLOTF2 (GSLICES * 256)       // floats per slot: 1024 pkts x 2
#define GPKF   (4 * RING * SLOTF2)   // 4 regions (2 layers x 2 phases)

// LDS-only phase barrier: orders part[] (LDS) across the block WITHOUT
// draining vmcnt -- packet stores / prefetched loads stay in flight.
#define PHASE_BAR() do {                                   \
    asm volatile("s_waitcnt lgkmcnt(0)" ::: "memory");     \
    __builtin_amdgcn_sched_barrier(0);                     \
    __builtin_amdgcn_s_barrier();                          \
    __builtin_amdgcn_sched_barrier(0);                     \
  } while (0)

// ---------------------------------------------------------------------------

// W transpose: WT[j][i] = W[i][j], 512x512
__global__ void transpose512(const float* __restrict__ in, float* __restrict__ out) {
  __shared__ float tile[32][33];
  int bx = blockIdx.x * 32, by = blockIdx.y * 32;
  int x = threadIdx.x, y0 = threadIdx.y;  // block (32,8)
  for (int dy = 0; dy < 32; dy += 8)
    tile[y0 + dy][x] = in[(size_t)(by + y0 + dy) * HH + bx + x];
  __syncthreads();
  for (int dy = 0; dy < 32; dy += 8)
    out[(size_t)(bx + y0 + dy) * HH + by + x] = tile[x][y0 + dy];
}

// Tiled GEMM with gather: C[m][n] = sum_k emb[x[m]][k] * Wn[n][k] + b1[n]+b2[n]
template <int K, bool GATHER>
__global__ __launch_bounds__(256) void xp_gemm(
    const float* __restrict__ Asrc, const int* __restrict__ xidx,
    const float* __restrict__ emb, const float* __restrict__ Wn,
    const float* __restrict__ bias1, const float* __restrict__ bias2,
    float* __restrict__ C) {
  const int tid = threadIdx.x;
  const int m0 = blockIdx.x * 64;
  const int n0 = blockIdx.y * 64;
  __shared__ alignas(16) float As[32][68];
  __shared__ alignas(16) float Bs[32][68];
  __shared__ int xs[64];
  if (GATHER) {
    if (tid < 64) xs[tid] = xidx[m0 + tid];
    __syncthreads();
  }
  float acc[4][4] = {};
  const int ty = tid >> 4, tx = tid & 15;
  const int row = tid >> 2;          // 0..63
  const int kc = (tid & 3) * 8;      // 0,8,16,24

  for (int k0 = 0; k0 < K; k0 += 32) {
    const float* ap;
    if (GATHER) ap = emb + (size_t)xs[row] * EE + (k0 + kc);
    else        ap = Asrc + (size_t)(m0 + row) * K + (k0 + kc);
    float4 av0 = *(const float4*)ap;
    float4 av1 = *(const float4*)(ap + 4);
    const float* bp = Wn + (size_t)(n0 + row) * K + (k0 + kc);
    float4 bv0 = *(const float4*)bp;
    float4 bv1 = *(const float4*)(bp + 4);
    __syncthreads();
    As[kc + 0][row] = av0.x; As[kc + 1][row] = av0.y;
    As[kc + 2][row] = av0.z; As[kc + 3][row] = av0.w;
    As[kc + 4][row] = av1.x; As[kc + 5][row] = av1.y;
    As[kc + 6][row] = av1.z; As[kc + 7][row] = av1.w;
    Bs[kc + 0][row] = bv0.x; Bs[kc + 1][row] = bv0.y;
    Bs[kc + 2][row] = bv0.z; Bs[kc + 3][row] = bv0.w;
    Bs[kc + 4][row] = bv1.x; Bs[kc + 5][row] = bv1.y;
    Bs[kc + 6][row] = bv1.z; Bs[kc + 7][row] = bv1.w;
    __syncthreads();
#pragma unroll 8
    for (int k = 0; k < 32; ++k) {
      float4 av = *(const float4*)&As[k][ty * 4];
      float4 bv = *(const float4*)&Bs[k][tx * 4];
      acc[0][0] += av.x * bv.x; acc[0][1] += av.x * bv.y;
      acc[0][2] += av.x * bv.z; acc[0][3] += av.x * bv.w;
      acc[1][0] += av.y * bv.x; acc[1][1] += av.y * bv.y;
      acc[1][2] += av.y * bv.z; acc[1][3] += av.y * bv.w;
      acc[2][0] += av.z * bv.x; acc[2][1] += av.z * bv.y;
      acc[2][2] += av.z * bv.z; acc[2][3] += av.z * bv.w;
      acc[3][0] += av.w * bv.x; acc[3][1] += av.w * bv.y;
      acc[3][2] += av.w * bv.z; acc[3][3] += av.w * bv.w;
    }
  }
  float bj[4];
#pragma unroll
  for (int j = 0; j < 4; ++j) {
    int n = n0 + tx * 4 + j;
    bj[j] = bias1[n] + bias2[n];
  }
#pragma unroll
  for (int i = 0; i < 4; ++i) {
    float4 cv = make_float4(acc[i][0] + bj[0], acc[i][1] + bj[1],
                            acc[i][2] + bj[2], acc[i][3] + bj[3]);
    *(float4*)&C[(size_t)(m0 + ty * 4 + i) * HH + n0 + tx * 4] = cv;
  }
}

// Zero packet region + barrier flags AT THE IC (grid-stride). Every launch.
__global__ void init_sync(float* __restrict__ pkts, unsigned* __restrict__ flags) {
  const size_t n = (size_t)NGROUPS * GPKF;
  const size_t stride = (size_t)gridDim.x * 256;
  for (size_t i = (size_t)blockIdx.x * 256 + threadIdx.x; i < n; i += stride)
    __hip_atomic_store(&pkts[i], 0.f, __ATOMIC_RELAXED, __HIP_MEMORY_SCOPE_SYSTEM);
  const size_t m = NGROUPS * LBLK * 32;
  for (size_t i = (size_t)blockIdx.x * 256 + threadIdx.x; i < m; i += stride)
    __hip_atomic_store(&flags[i], 0u, __ATOMIC_RELAXED, __HIP_MEMORY_SCOPE_SYSTEM);
}

__device__ __forceinline__ void fma4(float4& d, const float4 w, const float s) {
  d.x = __builtin_fmaf(w.x, s, d.x);
  d.y = __builtin_fmaf(w.y, s, d.y);
  d.z = __builtin_fmaf(w.z, s, d.z);
  d.w = __builtin_fmaf(w.w, s, d.w);
}

// Poll 2 packets (1 dwordx4); s_sleep backoff.
__device__ __forceinline__ float4 poll1(const float* p, unsigned tg) {
  float4 u;
  for (;;) {
    asm volatile("global_load_dwordx4 %0, %1, off sc0 sc1\n\ts_waitcnt vmcnt(0)"
                 : "=&v"(u) : "v"(p) : "memory");
    if (__float_as_uint(u.y) == tg && __float_as_uint(u.w) == tg) break;
    __builtin_amdgcn_s_sleep(1);
  }
  return u;
}

// Poll 2+2 packets from two regions in one retry loop.
__device__ __forceinline__ void poll1x2(const float* pa, unsigned tga,
                                        const float* pb, unsigned tgb,
                                        float4& a, float4& b) {
  for (;;) {
    asm volatile("global_load_dwordx4 %0, %2, off sc0 sc1\n\t"
                 "global_load_dwordx4 %1, %3, off sc0 sc1\n\t"
                 "s_waitcnt vmcnt(0)"
                 : "=&v"(a), "=&v"(b) : "v"(pa), "v"(pb) : "memory");
    if (__float_as_uint(a.y) == tga && __float_as_uint(a.w) == tga &&
        __float_as_uint(b.y) == tgb && __float_as_uint(b.w) == tgb) break;
    __builtin_amdgcn_s_sleep(1);
  }
}

// matvec over one phase's 2 batches from LDS h[2][HH]
__device__ __forceinline__ void fma_mv2(float4 acc[2], const float4 wreg[16],
                                        const float* h, int jg) {
#pragma unroll
  for (int q = 0; q < 4; ++q) {
    float4 w0 = wreg[q * 4 + 0], w1 = wreg[q * 4 + 1];
    float4 w2 = wreg[q * 4 + 2], w3 = wreg[q * 4 + 3];
#pragma unroll
    for (int b = 0; b < BPP; ++b) {
      float4 hv = *(const float4*)&h[b * HH + jg * 16 + q * 4];
      fma4(acc[b], w0, hv.x);
      fma4(acc[b], w1, hv.y);
      fma4(acc[b], w2, hv.z);
      fma4(acc[b], w3, hv.w);
    }
  }
}

// Fused 2-layer, 2-phase recurrence. bid: grp = bid&15, role = bid>>4
// (0..7 = L0 slices, 8..15 = L1 slices). Packet regions r = layer*2+phase.
__global__ __launch_bounds__(RECT, 2) void rec_fused(
    const float* __restrict__ xp,      // [BB][SS][HH]
    const float* __restrict__ WThh0,   // [HH][HH]
    const float* __restrict__ WTih1,   // [HH][HH]
    const float* __restrict__ WThh1,   // [HH][HH]
    const float* __restrict__ b_ih1,
    const float* __restrict__ b_hh1,
    float* __restrict__ pooled,        // [BB][HH]
    float* __restrict__ pkts,          // [NGROUPS][4][RING][SLOTF2]
    unsigned* __restrict__ flags) {    // [NGROUPS][LBLK][32]
  const int tid = threadIdx.x;
  const int bid = blockIdx.x;
  const int grp = bid & 15;
  const int role = bid >> 4;          // 0..15
  const bool isL1 = role >= GSLICES;
  const int slice = role & 7;
  const int oo4 = tid & 15;
  const int jg = tid >> 4;            // 0..31
  const int obase = slice * 64 + oo4 * 4;

  // ---- weights into registers (once); pin against remat (round-4 lesson) --
  float4 wregA[16], wregB[16];
  {
    const float* wb = isL1 ? WThh1 : WThh0;
#pragma unroll
    for (int j = 0; j < 16; ++j)
      wregB[j] = *(const float4*)&wb[(size_t)(jg * 16 + j) * HH + obase];
#pragma unroll
    for (int j = 0; j < 16; ++j)
      asm volatile("" : "+v"(wregB[j].x), "+v"(wregB[j].y),
                        "+v"(wregB[j].z), "+v"(wregB[j].w));
  }
  if (isL1) {
#pragma unroll
    for (int j = 0; j < 16; ++j)
      wregA[j] = *(const float4*)&WTih1[(size_t)(jg * 16 + j) * HH + obase];
#pragma unroll
    for (int j = 0; j < 16; ++j)
      asm volatile("" : "+v"(wregA[j].x), "+v"(wregA[j].y),
                        "+v"(wregA[j].z), "+v"(wregA[j].w));
  }

  float* pk = pkts + (size_t)grp * GPKF;
  unsigned* flg = flags + grp * (LBLK * 32);

  __shared__ alignas(16) float hs0A[BPP * HH];   // 4 KB each
  __shared__ alignas(16) float hs0B[BPP * HH];
  __shared__ alignas(16) float hs1A[BPP * HH];   // L1 only
  __shared__ alignas(16) float hs1B[BPP * HH];
  __shared__ float part[2][8][16][9];            // [phase][wave][oo4][b*4+c]

  const int wave = tid >> 6, wl = tid & 63;
  const int fo = tid & 63;
  const int fbb = (tid >> 6) & 3;          // batch (tid<256); wave == batch
  const int fbl = (tid >> 6) & 1;          // batch within phase
  const int fog = slice * 64 + fo;
  const size_t fxbase = (size_t)(grp * BPG + fbb) * (SS * HH) + fog;
  float pacc = 0.f;
  float bs = 0.f;
  if (tid < 256) bs = b_ih1[fog] + b_hh1[fog];

  const int toff = wave * 256 + wl * 4;           // consumer dwordx4 float off
  const int wpo = slice * 256 + fo * 4 + fbl * 2; // producer pkt float off

  for (int s = 0; s < SS; ++s) {
    float xv = 0.f;
    if (!isL1 && tid < 256) xv = xp[fxbase + (size_t)s * HH];

    // =============== PHASE A (batches 0,1) ===============
    if (s >= 1) {
      const float* p0 = pk + (size_t)((0 * RING) + ((s - 1) & (RING - 1))) * SLOTF2 + toff;
      if (!isL1) {
        float4 u = poll1(p0, (unsigned)s);
        hs0A[tid] = u.x; hs0A[HH + tid] = u.z;
      } else if (s >= 2) {
        const float* p1 = pk + (size_t)((2 * RING) + ((s - 2) & (RING - 1))) * SLOTF2 + toff;
        float4 a, b;
        poll1x2(p0, (unsigned)s, p1, (unsigned)(s - 1), a, b);
        hs0A[tid] = a.x; hs0A[HH + tid] = a.z;
        hs1A[tid] = b.x; hs1A[HH + tid] = b.z;
      } else {
        float4 a = poll1(p0, 1u);
        hs0A[tid] = a.x; hs0A[HH + tid] = a.z;
      }
    }
    asm volatile("s_waitcnt lgkmcnt(0)" ::: "memory");
    __builtin_amdgcn_sched_barrier(0);
    {
      float4 acc[BPP] = {{0,0,0,0},{0,0,0,0}};
      if (s >= 1) {
        if (!isL1) fma_mv2(acc, wregB, hs0A, jg);
        else {
          fma_mv2(acc, wregA, hs0A, jg);
          if (s >= 2) fma_mv2(acc, wregB, hs1A, jg);
        }
#pragma unroll
        for (int b = 0; b < BPP; ++b) {
          acc[b].x += __shfl_down(acc[b].x, 32); acc[b].y += __shfl_down(acc[b].y, 32);
          acc[b].z += __shfl_down(acc[b].z, 32); acc[b].w += __shfl_down(acc[b].w, 32);
          acc[b].x += __shfl_down(acc[b].x, 16); acc[b].y += __shfl_down(acc[b].y, 16);
          acc[b].z += __shfl_down(acc[b].z, 16); acc[b].w += __shfl_down(acc[b].w, 16);
        }
        if (wl < 16) {
#pragma unroll
          for (int b = 0; b < BPP; ++b) {
            part[0][wave][wl][b * 4 + 0] = acc[b].x;
            part[0][wave][wl][b * 4 + 1] = acc[b].y;
            part[0][wave][wl][b * 4 + 2] = acc[b].z;
            part[0][wave][wl][b * 4 + 3] = acc[b].w;
          }
        }
      }
    }
    PHASE_BAR();       // sync-A: LDS-only drain, packet stores stay in flight
    if (tid < 128) {   // finalize A (waves 0-1 = batches 0,1)
      if (!isL1) {
        float v = xv;
        if (s >= 1) {
#pragma unroll
          for (int w = 0; w < 8; ++w) v += part[0][w][fo >> 2][fbl * 4 + (fo & 3)];
        }
        float h = tanhf(v);
        float* pw = pk + (size_t)((0 * RING) + (s & (RING - 1))) * SLOTF2 + wpo;
        float2 pp; pp.x = h; pp.y = __uint_as_float((unsigned)(s + 1));
        asm volatile("global_store_dwordx2 %0, %1, off sc0 sc1"
                     :: "v"(pw), "v"(pp) : "memory");
      } else if (s >= 1) {
        float v = bs;
#pragma unroll
        for (int w = 0; w < 8; ++w) v += part[0][w][fo >> 2][fbl * 4 + (fo & 3)];
        float h = tanhf(v);
        pacc += h;
        float* pw = pk + (size_t)((2 * RING) + ((s - 1) & (RING - 1))) * SLOTF2 + wpo;
        float2 pp; pp.x = h; pp.y = __uint_as_float((unsigned)s);
        asm volatile("global_store_dwordx2 %0, %1, off sc0 sc1"
                     :: "v"(pw), "v"(pp) : "memory");
      }
    }

    // =============== PHASE B (batches 2,3) ===============
    if (s >= 1) {
      const float* p0 = pk + (size_t)((1 * RING) + ((s - 1) & (RING - 1))) * SLOTF2 + toff;
      if (!isL1) {
        float4 u = poll1(p0, (unsigned)s);
        hs0B[tid] = u.x; hs0B[HH + tid] = u.z;
      } else if (s >= 2) {
        const float* p1 = pk + (size_t)((3 * RING) + ((s - 2) & (RING - 1))) * SLOTF2 + toff;
        float4 a, b;
        poll1x2(p0, (unsigned)s, p1, (unsigned)(s - 1), a, b);
        hs0B[tid] = a.x; hs0B[HH + tid] = a.z;
        hs1B[tid] = b.x; hs1B[HH + tid] = b.z;
      } else {
        float4 a = poll1(p0, 1u);
        hs0B[tid] = a.x; hs0B[HH + tid] = a.z;
      }
    }
    asm volatile("s_waitcnt lgkmcnt(0)" ::: "memory");
    __builtin_amdgcn_sched_barrier(0);
    {
      float4 acc[BPP] = {{0,0,0,0},{0,0,0,0}};
      if (s >= 1) {
        if (!isL1) fma_mv2(acc, wregB, hs0B, jg);
        else {
          fma_mv2(acc, wregA, hs0B, jg);
          if (s >= 2) fma_mv2(acc, wregB, hs1B, jg);
        }
#pragma unroll
        for (int b = 0; b < BPP; ++b) {
          acc[b].x += __shfl_down(acc[b].x, 32); acc[b].y += __shfl_down(acc[b].y, 32);
          acc[b].z += __shfl_down(acc[b].z, 32); acc[b].w += __shfl_down(acc[b].w, 32);
          acc[b].x += __shfl_down(acc[b].x, 16); acc[b].y += __shfl_down(acc[b].y, 16);
          acc[b].z += __shfl_down(acc[b].z, 16); acc[b].w += __shfl_down(acc[b].w, 16);
        }
        if (wl < 16) {
#pragma unroll
          for (int b = 0; b < BPP; ++b) {
            part[1][wave][wl][b * 4 + 0] = acc[b].x;
            part[1][wave][wl][b * 4 + 1] = acc[b].y;
            part[1][wave][wl][b * 4 + 2] = acc[b].z;
            part[1][wave][wl][b * 4 + 3] = acc[b].w;
          }
        }
      }
    }
    PHASE_BAR();       // sync-B: LDS-only drain
    if (tid >= 128 && tid < 256) {   // finalize B (waves 2-3 = batches 2,3)
      if (!isL1) {
        float v = xv;
        if (s >= 1) {
#pragma unroll
          for (int w = 0; w < 8; ++w) v += part[1][w][fo >> 2][fbl * 4 + (fo & 3)];
        }
        float h = tanhf(v);
        float* pw = pk + (size_t)((1 * RING) + (s & (RING - 1))) * SLOTF2 + wpo;
        float2 pp; pp.x = h; pp.y = __uint_as_float((unsigned)(s + 1));
        asm volatile("global_store_dwordx2 %0, %1, off sc0 sc1"
                     :: "v"(pw), "v"(pp) : "memory");
      } else if (s >= 1) {
        float v = bs;
#pragma unroll
        for (int w = 0; w < 8; ++w) v += part[1][w][fo >> 2][fbl * 4 + (fo & 3)];
        float h = tanhf(v);
        pacc += h;
        float* pw = pk + (size_t)((3 * RING) + ((s - 1) & (RING - 1))) * SLOTF2 + wpo;
        float2 pp; pp.x = h; pp.y = __uint_as_float((unsigned)s);
        asm volatile("global_store_dwordx2 %0, %1, off sc0 sc1"
                     :: "v"(pw), "v"(pp) : "memory");
      }
    }

    // ---- periodic full barrier (skew bound: drift <= BARK < RING) ----
    if ((s & (BARK - 1)) == (BARK - 1)) {
      unsigned bt = (unsigned)((s >> 5) + 1);
      if (tid == 0) {
        unsigned* fp = flg + role * 32;
        asm volatile("global_store_dword %0, %1, off sc0 sc1"
                     :: "v"(fp), "v"(bt) : "memory");
      }
      if (tid < LBLK) {
        const unsigned* fp = flg + tid * 32;
        unsigned v;
        do {
          asm volatile("global_load_dword %0, %1, off sc0 sc1\n\ts_waitcnt vmcnt(0)"
                       : "=v"(v) : "v"(fp) : "memory");
          if (v < bt) __builtin_amdgcn_s_sleep(2);
        } while (v < bt);
      }
      __syncthreads();
    }
  }

  // ---- L1 epilogue: h1_511 per phase (h0_511 tag 512, h1_510 tag 511) ----
  if (isL1) {
    {
      const float* p0 = pk + (size_t)((0 * RING) + ((SS - 1) & (RING - 1))) * SLOTF2 + toff;
      const float* p1 = pk + (size_t)((2 * RING) + ((SS - 2) & (RING - 1))) * SLOTF2 + toff;
      float4 a, b;
      poll1x2(p0, (unsigned)SS, p1, (unsigned)(SS - 1), a, b);
      hs0A[tid] = a.x; hs0A[HH + tid] = a.z;
      hs1A[tid] = b.x; hs1A[HH + tid] = b.z;
      const float* q0 = pk + (size_t)((1 * RING) + ((SS - 1) & (RING - 1))) * SLOTF2 + toff;
      const float* q1 = pk + (size_t)((3 * RING) + ((SS - 2) & (RING - 1))) * SLOTF2 + toff;
      float4 c, d;
      poll1x2(q0, (unsigned)SS, q1, (unsigned)(SS - 1), c, d);
      hs0B[tid] = c.x; hs0B[HH + tid] = c.z;
      hs1B[tid] = d.x; hs1B[HH + tid] = d.z;
    }
    asm volatile("s_waitcnt lgkmcnt(0)" ::: "memory");
    __builtin_amdgcn_sched_barrier(0);
    for (int ph = 0; ph < 2; ++ph) {
      float4 acc[BPP] = {{0,0,0,0},{0,0,0,0}};
      const float* h0 = ph ? hs0B : hs0A;
      const float* h1 = ph ? hs1B : hs1A;
      fma_mv2(acc, wregA, h0, jg);
      fma_mv2(acc, wregB, h1, jg);
#pragma unroll
      for (int b = 0; b < BPP; ++b) {
        acc[b].x += __shfl_down(acc[b].x, 32); acc[b].y += __shfl_down(acc[b].y, 32);
        acc[b].z += __shfl_down(acc[b].z, 32); acc[b].w += __shfl_down(acc[b].w, 32);
        acc[b].x += __shfl_down(acc[b].x, 16); acc[b].y += __shfl_down(acc[b].y, 16);
        acc[b].z += __shfl_down(acc[b].z, 16); acc[b].w += __shfl_down(acc[b].w, 16);
      }
      if (wl < 16) {
#pragma unroll
        for (int b = 0; b < BPP; ++b) {
          part[ph][wave][wl][b * 4 + 0] = acc[b].x;
          part[ph][wave][wl][b * 4 + 1] = acc[b].y;
          part[ph][wave][wl][b * 4 + 2] = acc[b].z;
          part[ph][wave][wl][b * 4 + 3] = acc[b].w;
        }
      }
    }
    __syncthreads();
    if (tid < 256) {
      int ph = tid >> 7;
      float v = bs;
#pragma unroll
      for (int w = 0; w < 8; ++w) v += part[ph][w][fo >> 2][fbl * 4 + (fo & 3)];
      pacc += tanhf(v);
      pooled[(size_t)(grp * BPG + fbb) * HH + fog] = pacc * (1.0f / SS);
    }
  }
}

// Final head: out[b][c] = sum_k pooled[b][k] * W_out[c][k] + b_out[c]
__global__ void out_kernel(const float* __restrict__ pooled,
                           const float* __restrict__ W_out,
                           const float* __restrict__ b_out,
                           float* __restrict__ out) {
  int tid = threadIdx.x;
  if (tid >= BB * 2) return;
  int b = tid >> 1, c = tid & 1;
  float acc = b_out[c];
  for (int k = 0; k < HH; ++k)
    acc += pooled[(size_t)b * HH + k] * W_out[(size_t)c * HH + k];
  out[(size_t)b * 2 + c] = acc;
}

extern "C" void kernel_launch(void* const* d_in, const int* in_sizes, int n_in,
                              void* d_out, int out_size, void* d_ws, size_t ws_size,
                              hipStream_t stream) {
  const int*   x     = (const int*)d_in[0];
  const float* emb   = (const float*)d_in[1];
  const float* W_ih0 = (const float*)d_in[2];
  const float* W_hh0 = (const float*)d_in[3];
  const float* b_ih0 = (const float*)d_in[4];
  const float* b_hh0 = (const float*)d_in[5];
  const float* W_ih1 = (const float*)d_in[6];
  const float* W_hh1 = (const float*)d_in[7];
  const float* b_ih1 = (const float*)d_in[8];
  const float* b_hh1 = (const float*)d_in[9];
  const float* W_out = (const float*)d_in[10];
  const float* b_out = (const float*)d_in[11];

  float* ws = (float*)d_ws;
  const size_t NBSH = (size_t)BB * SS * HH;            // 16777216
  const size_t PKF  = (size_t)NGROUPS * GPKF;          // 8,388,608 floats (32MB)
  float* xp      = ws;                    // 64 MB
  float* WThh0   = ws + NBSH;             // 1 MB
  float* WTih1   = WThh0 + HH * HH;       // 1 MB
  float* WThh1   = WTih1 + HH * HH;       // 1 MB
  float* pooled  = WThh1 + HH * HH;       // 128 KB
  float* pkts    = pooled + BB * HH;      // 32 MB
  unsigned* flags = (unsigned*)(pkts + PKF);  // 32 KB

  init_sync<<<4096, 256, 0, stream>>>(pkts, flags);

  dim3 tb(32, 8), tg(16, 16);
  transpose512<<<tg, tb, 0, stream>>>(W_hh0, WThh0);
  transpose512<<<tg, tb, 0, stream>>>(W_ih1, WTih1);
  transpose512<<<tg, tb, 0, stream>>>(W_hh1, WThh1);

  dim3 gg(512, 8);
  xp_gemm<EE, true><<<gg, 256, 0, stream>>>(nullptr, x, emb, W_ih0, b_ih0, b_hh0, xp);
  rec_fused<<<NGROUPS * LBLK, RECT, 0, stream>>>(
      xp, WThh0, WTih1, WThh1, b_ih1, b_hh1, pooled, pkts, flags);
  out_kernel<<<1, 128, 0, stream>>>(pooled, W_out, b_out, (float*)d_out);
}

// Round 19
// 1678.097 us; speedup vs baseline: 1.0035x; 1.0035x over previous
//
#include <hip/hip_runtime.h>
#include <math.h>

// Problem constants
#define BB 64      // batch
#define SS 512     // seq
#define EE 256     // embed
#define HH 512     // hidden

// Round-19: RESTORE round-16 exactly (best proven: 1676us total, absmax 0).
// r18's counted-vmcnt prefetch crashed: hand-counted s_waitcnt vmcnt(N)
// depends on exact compiler VM-op materialization -- not robust at HIP
// source level. r12 (XCD-L2 exchange) hung: no architectural XCD-local
// exchange scope on gfx950. The proven design:
//   - fused 2-layer pipelined recurrence (L1 lags L0 by one step),
//     GEMM1 eliminated (W_ih1 slice lives in registers next to W_hh1)
//   - 16 groups x 16 blocks; W slices asm-pinned in VGPRs (zero weight
//     traffic across all 512 steps)
//   - LL {h,tag} 8-byte packets through the IC (store IS the release;
//     poll load IS the stage); wave-private poll->scat->FMA dataflow
//     (wave w's j-range == producer slice w), no stage barrier
//   - batch-phase pipelining (phase A = batches 0,1 / B = 2,3): one
//     phase's IC flight hides under the other phase's compute
//   - RING=64 slots, full flag-barrier every BARK=32 steps (drift bound)
#define NGROUPS 16
#define GSLICES 8          // slices per layer per group
#define LBLK 16            // blocks per group (2 layers x 8 slices)
#define BPG 4              // batches per group
#define BPP 2              // batches per phase
#define RECT 512           // threads per rec block
#define RING 64            // ring slots per (layer,phase) chain
#define BARK 32            // full barrier every BARK steps

#define SLOTF2 (GSLICES * 256)       // floats per slot: 1024 pkts x 2
#define GPKF   (4 * RING * SLOTF2)   // 4 regions (2 layers x 2 phases)

// ---------------------------------------------------------------------------

// W transpose: WT[j][i] = W[i][j], 512x512
__global__ void transpose512(const float* __restrict__ in, float* __restrict__ out) {
  __shared__ float tile[32][33];
  int bx = blockIdx.x * 32, by = blockIdx.y * 32;
  int x = threadIdx.x, y0 = threadIdx.y;  // block (32,8)
  for (int dy = 0; dy < 32; dy += 8)
    tile[y0 + dy][x] = in[(size_t)(by + y0 + dy) * HH + bx + x];
  __syncthreads();
  for (int dy = 0; dy < 32; dy += 8)
    out[(size_t)(bx + y0 + dy) * HH + by + x] = tile[x][y0 + dy];
}

// Tiled GEMM with gather: C[m][n] = sum_k emb[x[m]][k] * Wn[n][k] + b1[n]+b2[n]
template <int K, bool GATHER>
__global__ __launch_bounds__(256) void xp_gemm(
    const float* __restrict__ Asrc, const int* __restrict__ xidx,
    const float* __restrict__ emb, const float* __restrict__ Wn,
    const float* __restrict__ bias1, const float* __restrict__ bias2,
    float* __restrict__ C) {
  const int tid = threadIdx.x;
  const int m0 = blockIdx.x * 64;
  const int n0 = blockIdx.y * 64;
  __shared__ alignas(16) float As[32][68];
  __shared__ alignas(16) float Bs[32][68];
  __shared__ int xs[64];
  if (GATHER) {
    if (tid < 64) xs[tid] = xidx[m0 + tid];
    __syncthreads();
  }
  float acc[4][4] = {};
  const int ty = tid >> 4, tx = tid & 15;
  const int row = tid >> 2;          // 0..63
  const int kc = (tid & 3) * 8;      // 0,8,16,24

  for (int k0 = 0; k0 < K; k0 += 32) {
    const float* ap;
    if (GATHER) ap = emb + (size_t)xs[row] * EE + (k0 + kc);
    else        ap = Asrc + (size_t)(m0 + row) * K + (k0 + kc);
    float4 av0 = *(const float4*)ap;
    float4 av1 = *(const float4*)(ap + 4);
    const float* bp = Wn + (size_t)(n0 + row) * K + (k0 + kc);
    float4 bv0 = *(const float4*)bp;
    float4 bv1 = *(const float4*)(bp + 4);
    __syncthreads();
    As[kc + 0][row] = av0.x; As[kc + 1][row] = av0.y;
    As[kc + 2][row] = av0.z; As[kc + 3][row] = av0.w;
    As[kc + 4][row] = av1.x; As[kc + 5][row] = av1.y;
    As[kc + 6][row] = av1.z; As[kc + 7][row] = av1.w;
    Bs[kc + 0][row] = bv0.x; Bs[kc + 1][row] = bv0.y;
    Bs[kc + 2][row] = bv0.z; Bs[kc + 3][row] = bv0.w;
    Bs[kc + 4][row] = bv1.x; Bs[kc + 5][row] = bv1.y;
    Bs[kc + 6][row] = bv1.z; Bs[kc + 7][row] = bv1.w;
    __syncthreads();
#pragma unroll 8
    for (int k = 0; k < 32; ++k) {
      float4 av = *(const float4*)&As[k][ty * 4];
      float4 bv = *(const float4*)&Bs[k][tx * 4];
      acc[0][0] += av.x * bv.x; acc[0][1] += av.x * bv.y;
      acc[0][2] += av.x * bv.z; acc[0][3] += av.x * bv.w;
      acc[1][0] += av.y * bv.x; acc[1][1] += av.y * bv.y;
      acc[1][2] += av.y * bv.z; acc[1][3] += av.y * bv.w;
      acc[2][0] += av.z * bv.x; acc[2][1] += av.z * bv.y;
      acc[2][2] += av.z * bv.z; acc[2][3] += av.z * bv.w;
      acc[3][0] += av.w * bv.x; acc[3][1] += av.w * bv.y;
      acc[3][2] += av.w * bv.z; acc[3][3] += av.w * bv.w;
    }
  }
  float bj[4];
#pragma unroll
  for (int j = 0; j < 4; ++j) {
    int n = n0 + tx * 4 + j;
    bj[j] = bias1[n] + bias2[n];
  }
#pragma unroll
  for (int i = 0; i < 4; ++i) {
    float4 cv = make_float4(acc[i][0] + bj[0], acc[i][1] + bj[1],
                            acc[i][2] + bj[2], acc[i][3] + bj[3]);
    *(float4*)&C[(size_t)(m0 + ty * 4 + i) * HH + n0 + tx * 4] = cv;
  }
}

// Zero packet region + barrier flags AT THE IC (grid-stride). Every launch.
__global__ void init_sync(float* __restrict__ pkts, unsigned* __restrict__ flags) {
  const size_t n = (size_t)NGROUPS * GPKF;
  const size_t stride = (size_t)gridDim.x * 256;
  for (size_t i = (size_t)blockIdx.x * 256 + threadIdx.x; i < n; i += stride)
    __hip_atomic_store(&pkts[i], 0.f, __ATOMIC_RELAXED, __HIP_MEMORY_SCOPE_SYSTEM);
  const size_t m = NGROUPS * LBLK * 32;
  for (size_t i = (size_t)blockIdx.x * 256 + threadIdx.x; i < m; i += stride)
    __hip_atomic_store(&flags[i], 0u, __ATOMIC_RELAXED, __HIP_MEMORY_SCOPE_SYSTEM);
}

__device__ __forceinline__ void fma4(float4& d, const float4 w, const float s) {
  d.x = __builtin_fmaf(w.x, s, d.x);
  d.y = __builtin_fmaf(w.y, s, d.y);
  d.z = __builtin_fmaf(w.z, s, d.z);
  d.w = __builtin_fmaf(w.w, s, d.w);
}

// Poll 2 packets (1 dwordx4); s_sleep backoff.
__device__ __forceinline__ float4 poll1(const float* p, unsigned tg) {
  float4 u;
  for (;;) {
    asm volatile("global_load_dwordx4 %0, %1, off sc0 sc1\n\ts_waitcnt vmcnt(0)"
                 : "=&v"(u) : "v"(p) : "memory");
    if (__float_as_uint(u.y) == tg && __float_as_uint(u.w) == tg) break;
    __builtin_amdgcn_s_sleep(1);
  }
  return u;
}

// Poll 2+2 packets from two regions in one retry loop.
__device__ __forceinline__ void poll1x2(const float* pa, unsigned tga,
                                        const float* pb, unsigned tgb,
                                        float4& a, float4& b) {
  for (;;) {
    asm volatile("global_load_dwordx4 %0, %2, off sc0 sc1\n\t"
                 "global_load_dwordx4 %1, %3, off sc0 sc1\n\t"
                 "s_waitcnt vmcnt(0)"
                 : "=&v"(a), "=&v"(b) : "v"(pa), "v"(pb) : "memory");
    if (__float_as_uint(a.y) == tga && __float_as_uint(a.w) == tga &&
        __float_as_uint(b.y) == tgb && __float_as_uint(b.w) == tgb) break;
    __builtin_amdgcn_s_sleep(1);
  }
}

// matvec over one phase's 2 batches from LDS h[2][HH]
__device__ __forceinline__ void fma_mv2(float4 acc[2], const float4 wreg[16],
                                        const float* h, int jg) {
#pragma unroll
  for (int q = 0; q < 4; ++q) {
    float4 w0 = wreg[q * 4 + 0], w1 = wreg[q * 4 + 1];
    float4 w2 = wreg[q * 4 + 2], w3 = wreg[q * 4 + 3];
#pragma unroll
    for (int b = 0; b < BPP; ++b) {
      float4 hv = *(const float4*)&h[b * HH + jg * 16 + q * 4];
      fma4(acc[b], w0, hv.x);
      fma4(acc[b], w1, hv.y);
      fma4(acc[b], w2, hv.z);
      fma4(acc[b], w3, hv.w);
    }
  }
}

// Fused 2-layer, 2-phase recurrence. bid: grp = bid&15, role = bid>>4
// (0..7 = L0 slices, 8..15 = L1 slices). Packet regions r = layer*2+phase;
// chain tags per (layer,phase).
__global__ __launch_bounds__(RECT, 2) void rec_fused(
    const float* __restrict__ xp,      // [BB][SS][HH]
    const float* __restrict__ WThh0,   // [HH][HH]
    const float* __restrict__ WTih1,   // [HH][HH]
    const float* __restrict__ WThh1,   // [HH][HH]
    const float* __restrict__ b_ih1,
    const float* __restrict__ b_hh1,
    float* __restrict__ pooled,        // [BB][HH]
    float* __restrict__ pkts,          // [NGROUPS][4][RING][SLOTF2]
    unsigned* __restrict__ flags) {    // [NGROUPS][LBLK][32]
  const int tid = threadIdx.x;
  const int bid = blockIdx.x;
  const int grp = bid & 15;
  const int role = bid >> 4;          // 0..15
  const bool isL1 = role >= GSLICES;
  const int slice = role & 7;
  const int oo4 = tid & 15;
  const int jg = tid >> 4;            // 0..31
  const int obase = slice * 64 + oo4 * 4;

  // ---- weights into registers (once); pin against remat (round-4 lesson) --
  float4 wregA[16], wregB[16];
  {
    const float* wb = isL1 ? WThh1 : WThh0;
#pragma unroll
    for (int j = 0; j < 16; ++j)
      wregB[j] = *(const float4*)&wb[(size_t)(jg * 16 + j) * HH + obase];
#pragma unroll
    for (int j = 0; j < 16; ++j)
      asm volatile("" : "+v"(wregB[j].x), "+v"(wregB[j].y),
                        "+v"(wregB[j].z), "+v"(wregB[j].w));
  }
  if (isL1) {
#pragma unroll
    for (int j = 0; j < 16; ++j)
      wregA[j] = *(const float4*)&WTih1[(size_t)(jg * 16 + j) * HH + obase];
#pragma unroll
    for (int j = 0; j < 16; ++j)
      asm volatile("" : "+v"(wregA[j].x), "+v"(wregA[j].y),
                        "+v"(wregA[j].z), "+v"(wregA[j].w));
  }

  float* pk = pkts + (size_t)grp * GPKF;
  unsigned* flg = flags + grp * (LBLK * 32);

  __shared__ alignas(16) float hs0A[BPP * HH];   // 4 KB each
  __shared__ alignas(16) float hs0B[BPP * HH];
  __shared__ alignas(16) float hs1A[BPP * HH];   // L1 only
  __shared__ alignas(16) float hs1B[BPP * HH];
  __shared__ float part[2][8][16][9];            // [phase][wave][oo4][b*4+c]

  const int wave = tid >> 6, wl = tid & 63;
  const int fo = tid & 63;
  const int fbb = (tid >> 6) & 3;          // batch (tid<256); wave == batch
  const int fbl = (tid >> 6) & 1;          // batch within phase
  const int fog = slice * 64 + fo;
  const size_t fxbase = (size_t)(grp * BPG + fbb) * (SS * HH) + fog;
  float pacc = 0.f;
  float bs = 0.f;
  if (tid < 256) bs = b_ih1[fog] + b_hh1[fog];

  const int toff = wave * 256 + wl * 4;           // consumer dwordx4 float off
  const int wpo = slice * 256 + fo * 4 + fbl * 2; // producer pkt float off

  for (int s = 0; s < SS; ++s) {
    float xv = 0.f;
    if (!isL1 && tid < 256) xv = xp[fxbase + (size_t)s * HH];

    // =============== PHASE A (batches 0,1) ===============
    if (s >= 1) {
      const float* p0 = pk + (size_t)((0 * RING) + ((s - 1) & (RING - 1))) * SLOTF2 + toff;
      if (!isL1) {
        float4 u = poll1(p0, (unsigned)s);
        hs0A[tid] = u.x; hs0A[HH + tid] = u.z;
      } else if (s >= 2) {
        const float* p1 = pk + (size_t)((2 * RING) + ((s - 2) & (RING - 1))) * SLOTF2 + toff;
        float4 a, b;
        poll1x2(p0, (unsigned)s, p1, (unsigned)(s - 1), a, b);
        hs0A[tid] = a.x; hs0A[HH + tid] = a.z;
        hs1A[tid] = b.x; hs1A[HH + tid] = b.z;
      } else {
        float4 a = poll1(p0, 1u);
        hs0A[tid] = a.x; hs0A[HH + tid] = a.z;
      }
    }
    asm volatile("s_waitcnt lgkmcnt(0)" ::: "memory");
    __builtin_amdgcn_sched_barrier(0);
    {
      float4 acc[BPP] = {{0,0,0,0},{0,0,0,0}};
      if (s >= 1) {
        if (!isL1) fma_mv2(acc, wregB, hs0A, jg);
        else {
          fma_mv2(acc, wregA, hs0A, jg);
          if (s >= 2) fma_mv2(acc, wregB, hs1A, jg);
        }
#pragma unroll
        for (int b = 0; b < BPP; ++b) {
          acc[b].x += __shfl_down(acc[b].x, 32); acc[b].y += __shfl_down(acc[b].y, 32);
          acc[b].z += __shfl_down(acc[b].z, 32); acc[b].w += __shfl_down(acc[b].w, 32);
          acc[b].x += __shfl_down(acc[b].x, 16); acc[b].y += __shfl_down(acc[b].y, 16);
          acc[b].z += __shfl_down(acc[b].z, 16); acc[b].w += __shfl_down(acc[b].w, 16);
        }
        if (wl < 16) {
#pragma unroll
          for (int b = 0; b < BPP; ++b) {
            part[0][wave][wl][b * 4 + 0] = acc[b].x;
            part[0][wave][wl][b * 4 + 1] = acc[b].y;
            part[0][wave][wl][b * 4 + 2] = acc[b].z;
            part[0][wave][wl][b * 4 + 3] = acc[b].w;
          }
        }
      }
    }
    __syncthreads();   // sync-A
    if (tid < 128) {   // finalize A (waves 0-1 = batches 0,1)
      if (!isL1) {
        float v = xv;
        if (s >= 1) {
#pragma unroll
          for (int w = 0; w < 8; ++w) v += part[0][w][fo >> 2][fbl * 4 + (fo & 3)];
        }
        float h = tanhf(v);
        float* pw = pk + (size_t)((0 * RING) + (s & (RING - 1))) * SLOTF2 + wpo;
        float2 pp; pp.x = h; pp.y = __uint_as_float((unsigned)(s + 1));
        asm volatile("global_store_dwordx2 %0, %1, off sc0 sc1"
                     :: "v"(pw), "v"(pp) : "memory");
      } else if (s >= 1) {
        float v = bs;
#pragma unroll
        for (int w = 0; w < 8; ++w) v += part[0][w][fo >> 2][fbl * 4 + (fo & 3)];
        float h = tanhf(v);
        pacc += h;
        float* pw = pk + (size_t)((2 * RING) + ((s - 1) & (RING - 1))) * SLOTF2 + wpo;
        float2 pp; pp.x = h; pp.y = __uint_as_float((unsigned)s);
        asm volatile("global_store_dwordx2 %0, %1, off sc0 sc1"
                     :: "v"(pw), "v"(pp) : "memory");
      }
    }

    // =============== PHASE B (batches 2,3) ===============
    if (s >= 1) {
      const float* p0 = pk + (size_t)((1 * RING) + ((s - 1) & (RING - 1))) * SLOTF2 + toff;
      if (!isL1) {
        float4 u = poll1(p0, (unsigned)s);
        hs0B[tid] = u.x; hs0B[HH + tid] = u.z;
      } else if (s >= 2) {
        const float* p1 = pk + (size_t)((3 * RING) + ((s - 2) & (RING - 1))) * SLOTF2 + toff;
        float4 a, b;
        poll1x2(p0, (unsigned)s, p1, (unsigned)(s - 1), a, b);
        hs0B[tid] = a.x; hs0B[HH + tid] = a.z;
        hs1B[tid] = b.x; hs1B[HH + tid] = b.z;
      } else {
        float4 a = poll1(p0, 1u);
        hs0B[tid] = a.x; hs0B[HH + tid] = a.z;
      }
    }
    asm volatile("s_waitcnt lgkmcnt(0)" ::: "memory");
    __builtin_amdgcn_sched_barrier(0);
    {
      float4 acc[BPP] = {{0,0,0,0},{0,0,0,0}};
      if (s >= 1) {
        if (!isL1) fma_mv2(acc, wregB, hs0B, jg);
        else {
          fma_mv2(acc, wregA, hs0B, jg);
          if (s >= 2) fma_mv2(acc, wregB, hs1B, jg);
        }
#pragma unroll
        for (int b = 0; b < BPP; ++b) {
          acc[b].x += __shfl_down(acc[b].x, 32); acc[b].y += __shfl_down(acc[b].y, 32);
          acc[b].z += __shfl_down(acc[b].z, 32); acc[b].w += __shfl_down(acc[b].w, 32);
          acc[b].x += __shfl_down(acc[b].x, 16); acc[b].y += __shfl_down(acc[b].y, 16);
          acc[b].z += __shfl_down(acc[b].z, 16); acc[b].w += __shfl_down(acc[b].w, 16);
        }
        if (wl < 16) {
#pragma unroll
          for (int b = 0; b < BPP; ++b) {
            part[1][wave][wl][b * 4 + 0] = acc[b].x;
            part[1][wave][wl][b * 4 + 1] = acc[b].y;
            part[1][wave][wl][b * 4 + 2] = acc[b].z;
            part[1][wave][wl][b * 4 + 3] = acc[b].w;
          }
        }
      }
    }
    __syncthreads();   // sync-B
    if (tid >= 128 && tid < 256) {   // finalize B (waves 2-3 = batches 2,3)
      if (!isL1) {
        float v = xv;
        if (s >= 1) {
#pragma unroll
          for (int w = 0; w < 8; ++w) v += part[1][w][fo >> 2][fbl * 4 + (fo & 3)];
        }
        float h = tanhf(v);
        float* pw = pk + (size_t)((1 * RING) + (s & (RING - 1))) * SLOTF2 + wpo;
        float2 pp; pp.x = h; pp.y = __uint_as_float((unsigned)(s + 1));
        asm volatile("global_store_dwordx2 %0, %1, off sc0 sc1"
                     :: "v"(pw), "v"(pp) : "memory");
      } else if (s >= 1) {
        float v = bs;
#pragma unroll
        for (int w = 0; w < 8; ++w) v += part[1][w][fo >> 2][fbl * 4 + (fo & 3)];
        float h = tanhf(v);
        pacc += h;
        float* pw = pk + (size_t)((3 * RING) + ((s - 1) & (RING - 1))) * SLOTF2 + wpo;
        float2 pp; pp.x = h; pp.y = __uint_as_float((unsigned)s);
        asm volatile("global_store_dwordx2 %0, %1, off sc0 sc1"
                     :: "v"(pw), "v"(pp) : "memory");
      }
    }

    // ---- periodic full barrier (skew bound: drift <= BARK < RING) ----
    if ((s & (BARK - 1)) == (BARK - 1)) {
      unsigned bt = (unsigned)((s >> 5) + 1);
      if (tid == 0) {
        unsigned* fp = flg + role * 32;
        asm volatile("global_store_dword %0, %1, off sc0 sc1"
                     :: "v"(fp), "v"(bt) : "memory");
      }
      if (tid < LBLK) {
        const unsigned* fp = flg + tid * 32;
        unsigned v;
        do {
          asm volatile("global_load_dword %0, %1, off sc0 sc1\n\ts_waitcnt vmcnt(0)"
                       : "=v"(v) : "v"(fp) : "memory");
          if (v < bt) __builtin_amdgcn_s_sleep(2);
        } while (v < bt);
      }
      __syncthreads();
    }
  }

  // ---- L1 epilogue: h1_511 per phase (h0_511 tag 512, h1_510 tag 511) ----
  if (isL1) {
    {
      const float* p0 = pk + (size_t)((0 * RING) + ((SS - 1) & (RING - 1))) * SLOTF2 + toff;
      const float* p1 = pk + (size_t)((2 * RING) + ((SS - 2) & (RING - 1))) * SLOTF2 + toff;
      float4 a, b;
      poll1x2(p0, (unsigned)SS, p1, (unsigned)(SS - 1), a, b);
      hs0A[tid] = a.x; hs0A[HH + tid] = a.z;
      hs1A[tid] = b.x; hs1A[HH + tid] = b.z;
      const float* q0 = pk + (size_t)((1 * RING) + ((SS - 1) & (RING - 1))) * SLOTF2 + toff;
      const float* q1 = pk + (size_t)((3 * RING) + ((SS - 2) & (RING - 1))) * SLOTF2 + toff;
      float4 c, d;
      poll1x2(q0, (unsigned)SS, q1, (unsigned)(SS - 1), c, d);
      hs0B[tid] = c.x; hs0B[HH + tid] = c.z;
      hs1B[tid] = d.x; hs1B[HH + tid] = d.z;
    }
    asm volatile("s_waitcnt lgkmcnt(0)" ::: "memory");
    __builtin_amdgcn_sched_barrier(0);
    for (int ph = 0; ph < 2; ++ph) {
      float4 acc[BPP] = {{0,0,0,0},{0,0,0,0}};
      const float* h0 = ph ? hs0B : hs0A;
      const float* h1 = ph ? hs1B : hs1A;
      fma_mv2(acc, wregA, h0, jg);
      fma_mv2(acc, wregB, h1, jg);
#pragma unroll
      for (int b = 0; b < BPP; ++b) {
        acc[b].x += __shfl_down(acc[b].x, 32); acc[b].y += __shfl_down(acc[b].y, 32);
        acc[b].z += __shfl_down(acc[b].z, 32); acc[b].w += __shfl_down(acc[b].w, 32);
        acc[b].x += __shfl_down(acc[b].x, 16); acc[b].y += __shfl_down(acc[b].y, 16);
        acc[b].z += __shfl_down(acc[b].z, 16); acc[b].w += __shfl_down(acc[b].w, 16);
      }
      if (wl < 16) {
#pragma unroll
        for (int b = 0; b < BPP; ++b) {
          part[ph][wave][wl][b * 4 + 0] = acc[b].x;
          part[ph][wave][wl][b * 4 + 1] = acc[b].y;
          part[ph][wave][wl][b * 4 + 2] = acc[b].z;
          part[ph][wave][wl][b * 4 + 3] = acc[b].w;
        }
      }
    }
    __syncthreads();
    if (tid < 256) {
      int ph = tid >> 7;
      float v = bs;
#pragma unroll
      for (int w = 0; w < 8; ++w) v += part[ph][w][fo >> 2][fbl * 4 + (fo & 3)];
      pacc += tanhf(v);
      pooled[(size_t)(grp * BPG + fbb) * HH + fog] = pacc * (1.0f / SS);
    }
  }
}

// Final head: out[b][c] = sum_k pooled[b][k] * W_out[c][k] + b_out[c]
__global__ void out_kernel(const float* __restrict__ pooled,
                           const float* __restrict__ W_out,
                           const float* __restrict__ b_out,
                           float* __restrict__ out) {
  int tid = threadIdx.x;
  if (tid >= BB * 2) return;
  int b = tid >> 1, c = tid & 1;
  float acc = b_out[c];
  for (int k = 0; k < HH; ++k)
    acc += pooled[(size_t)b * HH + k] * W_out[(size_t)c * HH + k];
  out[(size_t)b * 2 + c] = acc;
}

extern "C" void kernel_launch(void* const* d_in, const int* in_sizes, int n_in,
                              void* d_out, int out_size, void* d_ws, size_t ws_size,
                              hipStream_t stream) {
  const int*   x     = (const int*)d_in[0];
  const float* emb   = (const float*)d_in[1];
  const float* W_ih0 = (const float*)d_in[2];
  const float* W_hh0 = (const float*)d_in[3];
  const float* b_ih0 = (const float*)d_in[4];
  const float* b_hh0 = (const float*)d_in[5];
  const float* W_ih1 = (const float*)d_in[6];
  const float* W_hh1 = (const float*)d_in[7];
  const float* b_ih1 = (const float*)d_in[8];
  const float* b_hh1 = (const float*)d_in[9];
  const float* W_out = (const float*)d_in[10];
  const float* b_out = (const float*)d_in[11];

  float* ws = (float*)d_ws;
  const size_t NBSH = (size_t)BB * SS * HH;            // 16777216
  const size_t PKF  = (size_t)NGROUPS * GPKF;          // 8,388,608 floats (32MB)
  float* xp      = ws;                    // 64 MB
  float* WThh0   = ws + NBSH;             // 1 MB
  float* WTih1   = WThh0 + HH * HH;       // 1 MB
  float* WThh1   = WTih1 + HH * HH;       // 1 MB
  float* pooled  = WThh1 + HH * HH;       // 128 KB
  float* pkts    = pooled + BB * HH;      // 32 MB
  unsigned* flags = (unsigned*)(pkts + PKF);  // 32 KB

  init_sync<<<4096, 256, 0, stream>>>(pkts, flags);

  dim3 tb(32, 8), tg(16, 16);
  transpose512<<<tg, tb, 0, stream>>>(W_hh0, WThh0);
  transpose512<<<tg, tb, 0, stream>>>(W_ih1, WTih1);
  transpose512<<<tg, tb, 0, stream>>>(W_hh1, WThh1);

  dim3 gg(512, 8);
  xp_gemm<EE, true><<<gg, 256, 0, stream>>>(nullptr, x, emb, W_ih0, b_ih0, b_hh0, xp);
  rec_fused<<<NGROUPS * LBLK, RECT, 0, stream>>>(
      xp, WThh0, WTih1, WThh1, b_ih1, b_hh1, pooled, pkts, flags);
  out_kernel<<<1, 128, 0, stream>>>(pooled, W_out, b_out, (float*)d_out);
}